// Round 1
// baseline (331.468 us; speedup 1.0000x reference)
//
#include <hip/hip_runtime.h>
#include <math.h>

#define R_BINS 64
#define Z_BINS 64
#define NBINS (R_BINS * Z_BINS)

static constexpr float DR     = 10.0f / 64.0f;   // 0.15625 (exact in fp32)
static constexpr float DZ     = 4.0f  / 64.0f;   // 0.0625  (exact in fp32)
static constexpr float INV_DR = 64.0f / 10.0f;   // 6.4
static constexpr float INV_DZ = 16.0f;           // exact
static constexpr float ZMIN   = -2.0f;

// Histogram: grid-stride over quads of 4 particles. positions are interleaved
// xyz, so 3 consecutive float4 loads cover exactly 4 particles. Block-private
// LDS histogram, then skip-zero drain to the global accumulator in d_ws.
__global__ __launch_bounds__(256) void hist_kernel(const float4* __restrict__ pos4,
                                                   const float4* __restrict__ mass4,
                                                   float* __restrict__ gbins,
                                                   int nquads) {
    __shared__ float lbins[NBINS];
    for (int b = threadIdx.x; b < NBINS; b += blockDim.x) lbins[b] = 0.0f;
    __syncthreads();

    const int stride = gridDim.x * blockDim.x;
    for (int q = blockIdx.x * blockDim.x + threadIdx.x; q < nquads; q += stride) {
        const float4 p0 = pos4[3 * q + 0];
        const float4 p1 = pos4[3 * q + 1];
        const float4 p2 = pos4[3 * q + 2];
        const float4 m  = mass4[q];

        // particle k: (x,y,z) laid out across the 12 floats
        const float xs[4] = {p0.x, p0.w, p1.z, p2.y};
        const float ys[4] = {p0.y, p1.x, p1.w, p2.z};
        const float zs[4] = {p0.z, p1.y, p2.x, p2.w};
        const float ms[4] = {m.x, m.y, m.z, m.w};

#pragma unroll
        for (int k = 0; k < 4; ++k) {
            const float r = sqrtf(xs[k] * xs[k] + ys[k] * ys[k]);
            const int i = (int)floorf(r * INV_DR);                 // r >= 0 -> i >= 0
            const int j = (int)floorf((zs[k] - ZMIN) * INV_DZ);
            if (i < R_BINS && (unsigned)j < (unsigned)Z_BINS) {
                atomicAdd(&lbins[i * Z_BINS + j], ms[k]);
            }
        }
    }

    __syncthreads();
    for (int b = threadIdx.x; b < NBINS; b += blockDim.x) {
        const float v = lbins[b];
        if (v != 0.0f) atomicAdd(&gbins[b], v);
    }
}

// surface_density = mass_in_bin / (pi*(r1^2 - r0^2) * DZ)
__global__ __launch_bounds__(256) void finalize_kernel(const float* __restrict__ gbins,
                                                       float* __restrict__ out) {
    const int idx = blockIdx.x * blockDim.x + threadIdx.x;
    if (idx < NBINS) {
        const int i = idx / Z_BINS;
        const float r0 = (float)i * DR;
        const float r1 = (float)(i + 1) * DR;
        const float area = (float)M_PI * (r1 * r1 - r0 * r0);
        out[idx] = gbins[idx] / (area * DZ);
    }
}

extern "C" void kernel_launch(void* const* d_in, const int* in_sizes, int n_in,
                              void* d_out, int out_size, void* d_ws, size_t ws_size,
                              hipStream_t stream) {
    const float* positions = (const float*)d_in[0];  // (N,3) interleaved xyz
    const float* masses    = (const float*)d_in[1];  // (N,)
    float* out   = (float*)d_out;                    // (64*64,)
    float* gbins = (float*)d_ws;                     // 16 KB accumulator

    const int n = in_sizes[1];      // N particles
    const int nquads = n / 4;       // N = 16777216 is divisible by 4

    // d_ws is re-poisoned to 0xAA before every timed call — zero it.
    hipMemsetAsync(gbins, 0, NBINS * sizeof(float), stream);

    const int block = 256;
    const int grid  = 1024;         // 256 CUs x 4 blocks, 16 quads/thread
    hist_kernel<<<grid, block, 0, stream>>>((const float4*)positions,
                                            (const float4*)masses,
                                            gbins, nquads);

    finalize_kernel<<<(NBINS + block - 1) / block, block, 0, stream>>>(gbins, out);
}

// Round 2
// 327.649 us; speedup vs baseline: 1.0117x; 1.0117x over previous
//
#include <hip/hip_runtime.h>
#include <math.h>

#define R_BINS 64
#define Z_BINS 64
#define NBINS (R_BINS * Z_BINS)
#define BLOCK 512
#define WAVES_PER_BLOCK 8
#define GRID 1024

static constexpr float DR     = 10.0f / 64.0f;   // 0.15625 (exact in fp32)
static constexpr float DZ     = 4.0f  / 64.0f;   // 0.0625  (exact in fp32)
static constexpr float INV_DR = 6.4f;
static constexpr float INV_DZ = 16.0f;

// Each wave processes contiguous 256-particle chunks:
//  - 3x fully-coalesced float4 loads (1 KB each) of the interleaved xyz stream
//  - 4x fully-coalesced scalar mass loads
//  - AoS->SoA transpose through a per-wave 3 KB LDS stage (wave-local sync only)
//  - stride-3 scalar LDS reads (conflict-free: gcd(3,32)=1)
//  - block-private LDS histogram, skip-zero atomic drain to gbins
__global__ __launch_bounds__(BLOCK) void hist_kernel(const float4* __restrict__ pos4,
                                                     const float* __restrict__ mass,
                                                     float* __restrict__ gbins,
                                                     int nchunks) {
    __shared__ float lbins[NBINS];                    // 16 KB
    __shared__ float4 stage[WAVES_PER_BLOCK][192];    // 24 KB (3 KB / wave)

    const int lane = threadIdx.x & 63;
    const int w    = threadIdx.x >> 6;

    for (int b = threadIdx.x; b < NBINS; b += BLOCK) lbins[b] = 0.0f;
    __syncthreads();

    const int totalWaves = gridDim.x * WAVES_PER_BLOCK;
    float* s = (float*)&stage[w][0];                  // 768 floats = 256 particles

    for (int c = blockIdx.x * WAVES_PER_BLOCK + w; c < nchunks; c += totalWaves) {
        const float4* pb = pos4 + (size_t)192 * c;
        const float4 f0 = pb[lane];
        const float4 f1 = pb[64 + lane];
        const float4 f2 = pb[128 + lane];

        const float* mb = mass + (size_t)256 * c;
        const float m0 = mb[lane];
        const float m1 = mb[64 + lane];
        const float m2 = mb[128 + lane];
        const float m3 = mb[192 + lane];

        stage[w][lane]       = f0;
        stage[w][64 + lane]  = f1;
        stage[w][128 + lane] = f2;
        // Wave-local write->read ordering: LDS pipe is in-order per wave; pin
        // compiler ordering + drain lgkm before cross-lane readback.
        __asm__ volatile("s_waitcnt lgkmcnt(0)" ::: "memory");
        __builtin_amdgcn_wave_barrier();

        const float ms[4] = {m0, m1, m2, m3};
#pragma unroll
        for (int k = 0; k < 4; ++k) {
            const int p = 64 * k + lane;              // strided particle pick
            const float x = s[3 * p];
            const float y = s[3 * p + 1];
            const float z = s[3 * p + 2];
            const float r = sqrtf(x * x + y * y);
            const int i = (int)(r * INV_DR);          // r >= 0, trunc == floor
            const int j = (int)floorf((z + 2.0f) * INV_DZ);
            if (i < R_BINS && (unsigned)j < (unsigned)Z_BINS) {
                atomicAdd(&lbins[i * Z_BINS + j], ms[k]);
            }
        }
        // read-before-next-write ordering (in-order LDS pipe; pin compiler)
        __asm__ volatile("" ::: "memory");
        __builtin_amdgcn_wave_barrier();
    }

    __syncthreads();
    for (int b = threadIdx.x; b < NBINS; b += BLOCK) {
        const float v = lbins[b];
        if (v != 0.0f) atomicAdd(&gbins[b], v);
    }
}

// Tail for n % 256 != 0 (not hit at N=16777216; kept for robustness)
__global__ void tail_kernel(const float* __restrict__ pos,
                            const float* __restrict__ mass,
                            float* __restrict__ gbins,
                            int start, int n) {
    const int t = start + blockIdx.x * blockDim.x + threadIdx.x;
    if (t < n) {
        const float x = pos[3 * t], y = pos[3 * t + 1], z = pos[3 * t + 2];
        const float r = sqrtf(x * x + y * y);
        const int i = (int)(r * INV_DR);
        const int j = (int)floorf((z + 2.0f) * INV_DZ);
        if (i < R_BINS && (unsigned)j < (unsigned)Z_BINS) {
            atomicAdd(&gbins[i * Z_BINS + j], mass[t]);
        }
    }
}

__global__ __launch_bounds__(256) void finalize_kernel(const float* __restrict__ gbins,
                                                       float* __restrict__ out) {
    const int idx = blockIdx.x * blockDim.x + threadIdx.x;
    if (idx < NBINS) {
        const int i = idx / Z_BINS;
        const float r0 = (float)i * DR;
        const float r1 = (float)(i + 1) * DR;
        const float area = (float)M_PI * (r1 * r1 - r0 * r0);
        out[idx] = gbins[idx] / (area * DZ);
    }
}

extern "C" void kernel_launch(void* const* d_in, const int* in_sizes, int n_in,
                              void* d_out, int out_size, void* d_ws, size_t ws_size,
                              hipStream_t stream) {
    const float* positions = (const float*)d_in[0];  // (N,3) interleaved xyz
    const float* masses    = (const float*)d_in[1];  // (N,)
    float* out   = (float*)d_out;                    // (64*64,)
    float* gbins = (float*)d_ws;                     // 16 KB accumulator

    const int n = in_sizes[1];
    const int nchunks = n / 256;
    const int rem = n - nchunks * 256;

    // d_ws is re-poisoned to 0xAA before every timed call — zero it.
    hipMemsetAsync(gbins, 0, NBINS * sizeof(float), stream);

    hist_kernel<<<GRID, BLOCK, 0, stream>>>((const float4*)positions, masses,
                                            gbins, nchunks);
    if (rem > 0) {
        tail_kernel<<<(rem + 255) / 256, 256, 0, stream>>>(positions, masses,
                                                           gbins, nchunks * 256, n);
    }
    finalize_kernel<<<(NBINS + 255) / 256, 256, 0, stream>>>(gbins, out);
}